// Round 1
// baseline (410.308 us; speedup 1.0000x reference)
//
#include <hip/hip_runtime.h>

// Problem constants (from reference): D=64 features, EPS=0.5 residual scale.
constexpr int D = 64;
constexpr float EPS = 0.5f;

// deg[src[e]] += 1 for each edge (compiler coalesces per-wave same-address atomics)
__global__ void deg_kernel(const int* __restrict__ src, int* __restrict__ deg, int E) {
    int e = blockIdx.x * blockDim.x + threadIdx.x;
    if (e < E) atomicAdd(&deg[src[e]], 1);
}

// norm[i] = max(deg,1)^(-1/2)
__global__ void norm_kernel(const int* __restrict__ deg, float* __restrict__ norm, int n) {
    int i = blockIdx.x * blockDim.x + threadIdx.x;
    if (i < n) {
        float d = (float)deg[i];
        norm[i] = rsqrtf(fmaxf(d, 1.0f));
    }
}

// out = x * EPS  (residual term), vectorized float4
__global__ void init_out_kernel(const float4* __restrict__ x, float4* __restrict__ out, int n4) {
    int i = blockIdx.x * blockDim.x + threadIdx.x;
    if (i < n4) {
        float4 v = x[i];
        out[i] = make_float4(v.x * EPS, v.y * EPS, v.z * EPS, v.w * EPS);
    }
}

// One thread per (edge, feature). Wave (64 lanes) == one edge row:
//   - src/dst/norm loads are wave-uniform (broadcast, no divergence)
//   - x row read is one coalesced 256B transaction
//   - atomicAdd scatter to out row is a coalesced 256B atomic burst
__global__ void scatter_kernel(const float* __restrict__ x,
                               const int* __restrict__ src,
                               const int* __restrict__ dst,
                               const float* __restrict__ norm,
                               float* __restrict__ out, int E) {
    long long tid = (long long)blockIdx.x * blockDim.x + threadIdx.x;
    int e = (int)(tid >> 6);
    int d = (int)(tid & 63);
    if (e < E) {
        int s = src[e];
        int t = dst[e];
        float en = norm[s] * norm[t];
        float val = x[(long long)s * D + d] * en;
        atomicAdd(&out[(long long)t * D + d], val);
    }
}

extern "C" void kernel_launch(void* const* d_in, const int* in_sizes, int n_in,
                              void* d_out, int out_size, void* d_ws, size_t ws_size,
                              hipStream_t stream) {
    const float* x   = (const float*)d_in[0];
    const int*   src = (const int*)d_in[1];
    const int*   dst = (const int*)d_in[2];
    float* out = (float*)d_out;

    const int ND = in_sizes[0];      // N * D
    const int E  = in_sizes[1];
    const int n  = ND / D;           // N

    // Workspace layout: [0, N) ints -> deg ; [N, 2N) floats -> norm
    int*   deg  = (int*)d_ws;
    float* norm = (float*)d_ws + n;

    // deg must start at zero every call (ws is poisoned to 0xAA each call)
    hipMemsetAsync(deg, 0, (size_t)n * sizeof(int), stream);

    constexpr int B = 256;
    deg_kernel<<<(E + B - 1) / B, B, 0, stream>>>(src, deg, E);
    norm_kernel<<<(n + B - 1) / B, B, 0, stream>>>(deg, norm, n);

    int n4 = ND / 4;
    init_out_kernel<<<(n4 + B - 1) / B, B, 0, stream>>>((const float4*)x, (float4*)out, n4);

    long long total = (long long)E * D;
    int grid = (int)((total + B - 1) / B);
    scatter_kernel<<<grid, B, 0, stream>>>(x, src, dst, norm, out, E);
}

// Round 2
// 353.005 us; speedup vs baseline: 1.1623x; 1.1623x over previous
//
#include <hip/hip_runtime.h>

// GCN aggregation: out = segsum_dst( x[src] * norm[src]*norm[dst] ) + EPS*x
// Strategy: build dst-CSR (no float atomics), then one wave per node gathers.
constexpr int D = 64;
constexpr float EPS = 0.5f;
constexpr int SCAN_B = 1024;   // scan block width (N=100K -> 98 blocks, fits single-block pass 2)

// Per-edge histograms: out-degree (by src, for norm) and in-degree (by dst, for CSR)
__global__ void hist_kernel(const int* __restrict__ src, const int* __restrict__ dst,
                            int* __restrict__ deg_src, int* __restrict__ deg_dst, int E) {
    int e = blockIdx.x * blockDim.x + threadIdx.x;
    if (e < E) {
        atomicAdd(&deg_src[src[e]], 1);
        atomicAdd(&deg_dst[dst[e]], 1);
    }
}

__global__ void norm_kernel(const int* __restrict__ deg_src, float* __restrict__ norm, int n) {
    int i = blockIdx.x * blockDim.x + threadIdx.x;
    if (i < n) norm[i] = rsqrtf(fmaxf((float)deg_src[i], 1.0f));
}

// Scan pass 1: per-block inclusive scan (Hillis-Steele in LDS), emit exclusive + block totals
__global__ void scan1_kernel(const int* __restrict__ deg_dst, int* __restrict__ row_excl,
                             int* __restrict__ block_sums, int n) {
    __shared__ int sh[SCAN_B];
    int i = blockIdx.x * SCAN_B + threadIdx.x;
    int v = (i < n) ? deg_dst[i] : 0;
    sh[threadIdx.x] = v;
    __syncthreads();
    for (int off = 1; off < SCAN_B; off <<= 1) {
        int t = (threadIdx.x >= off) ? sh[threadIdx.x - off] : 0;
        __syncthreads();
        sh[threadIdx.x] += t;
        __syncthreads();
    }
    if (i < n) row_excl[i] = sh[threadIdx.x] - v;          // exclusive
    if (threadIdx.x == SCAN_B - 1) block_sums[blockIdx.x] = sh[SCAN_B - 1];
}

// Scan pass 2: single block exclusive-scans the block totals (S <= 1024)
__global__ void scan2_kernel(int* __restrict__ block_sums, int S) {
    __shared__ int sh[SCAN_B];
    int v = (threadIdx.x < S) ? block_sums[threadIdx.x] : 0;
    sh[threadIdx.x] = v;
    __syncthreads();
    for (int off = 1; off < SCAN_B; off <<= 1) {
        int t = (threadIdx.x >= off) ? sh[threadIdx.x - off] : 0;
        __syncthreads();
        sh[threadIdx.x] += t;
        __syncthreads();
    }
    if (threadIdx.x < S) block_sums[threadIdx.x] = sh[threadIdx.x] - v;  // exclusive
}

// Scan pass 3: add block offsets; also init cursor = row_ptr
__global__ void scan3_kernel(int* __restrict__ row_excl, const int* __restrict__ block_sums,
                             int* __restrict__ cursor, int n) {
    int i = blockIdx.x * SCAN_B + threadIdx.x;
    if (i < n) {
        int r = row_excl[i] + block_sums[blockIdx.x];
        row_excl[i] = r;
        cursor[i] = r;
    }
}

// CSR fill: bump cursor[dst], record src. Order within a node is irrelevant (sum).
// After this, cursor[t] == row_ptr[t] + in_degree(t) == row end.
__global__ void fill_kernel(const int* __restrict__ src, const int* __restrict__ dst,
                            int* __restrict__ cursor, int* __restrict__ csr_src, int E) {
    int e = blockIdx.x * blockDim.x + threadIdx.x;
    if (e < E) {
        int pos = atomicAdd(&cursor[dst[e]], 1);
        csr_src[pos] = src[e];
    }
}

// One wave per node: lane = feature. Registers accumulate; single coalesced out write
// fused with the EPS*x residual. csr_src/norm loads are wave-uniform (HW broadcast);
// x row loads are coalesced 256B.
__global__ void gather_kernel(const float* __restrict__ x, const int* __restrict__ csr_src,
                              const int* __restrict__ row_ptr, const int* __restrict__ row_end,
                              const float* __restrict__ norm, float* __restrict__ out, int n) {
    int node = blockIdx.x * (blockDim.x >> 6) + (threadIdx.x >> 6);
    int lane = threadIdx.x & 63;
    if (node >= n) return;
    int k   = row_ptr[node];
    int end = row_end[node];
    float acc = 0.0f;
    // 2x unroll for independent loads in flight
    for (; k + 1 < end; k += 2) {
        int s0 = csr_src[k], s1 = csr_src[k + 1];
        float n0 = norm[s0], n1 = norm[s1];
        float x0 = x[(size_t)s0 * D + lane];
        float x1 = x[(size_t)s1 * D + lane];
        acc += n0 * x0 + n1 * x1;
    }
    if (k < end) {
        int s = csr_src[k];
        acc += norm[s] * x[(size_t)s * D + lane];
    }
    out[(size_t)node * D + lane] = acc * norm[node] + EPS * x[(size_t)node * D + lane];
}

extern "C" void kernel_launch(void* const* d_in, const int* in_sizes, int n_in,
                              void* d_out, int out_size, void* d_ws, size_t ws_size,
                              hipStream_t stream) {
    const float* x   = (const float*)d_in[0];
    const int*   src = (const int*)d_in[1];
    const int*   dst = (const int*)d_in[2];
    float* out = (float*)d_out;

    const int ND = in_sizes[0];    // N * D
    const int E  = in_sizes[1];
    const int n  = ND / D;         // N
    const int S  = (n + SCAN_B - 1) / SCAN_B;   // scan blocks (98 for N=100K)

    // Workspace layout (ints/floats, 4B each):
    int*   deg_src    = (int*)d_ws;                 // [0, n)
    int*   deg_dst    = deg_src + n;                // [n, 2n)   (contiguous w/ deg_src for one memset)
    float* norm       = (float*)(deg_dst + n);      // [2n, 3n)
    int*   row_ptr    = (int*)(norm + n);           // [3n, 4n)
    int*   cursor     = row_ptr + n;                // [4n, 5n)
    int*   block_sums = cursor + n;                 // [5n, 5n+S)
    int*   csr_src    = block_sums + ((S + 63) & ~63); // padded, then E ints

    hipMemsetAsync(deg_src, 0, (size_t)2 * n * sizeof(int), stream);

    constexpr int B = 256;
    hist_kernel<<<(E + B - 1) / B, B, 0, stream>>>(src, dst, deg_src, deg_dst, E);
    norm_kernel<<<(n + B - 1) / B, B, 0, stream>>>(deg_src, norm, n);
    scan1_kernel<<<S, SCAN_B, 0, stream>>>(deg_dst, row_ptr, block_sums, n);
    scan2_kernel<<<1, SCAN_B, 0, stream>>>(block_sums, S);
    scan3_kernel<<<S, SCAN_B, 0, stream>>>(row_ptr, block_sums, cursor, n);
    fill_kernel<<<(E + B - 1) / B, B, 0, stream>>>(src, dst, cursor, csr_src, E);

    // 4 nodes (waves) per 256-thread block
    gather_kernel<<<(n + 3) / 4, B, 0, stream>>>(x, csr_src, row_ptr, cursor, norm, out, n);
}

// Round 3
// 310.680 us; speedup vs baseline: 1.3207x; 1.1362x over previous
//
#include <hip/hip_runtime.h>

// GCN aggregation: out = segsum_dst( x[src] * norm[src]*norm[dst] ) + EPS*x
// Round 3: fixed-slot CSR — the fill cursor doubles as the in-degree histogram,
// deleting the deg_dst atomic pass and the 3-kernel scan. Edge-ops drop 3->2 per edge.
constexpr int D = 64;
constexpr float EPS = 0.5f;
constexpr int SCAN_B = 1024;
constexpr int MAXOVF = 65536;   // overflow edge capacity (expected usage: 0)

// ---------------- Path A: fixed-slot CSR ----------------

// out-degree histogram (for norm): 1 fire-and-forget atomic per edge
__global__ void hist_src_kernel(const int* __restrict__ src, int* __restrict__ deg_src, int E) {
    int e = blockIdx.x * blockDim.x + threadIdx.x;
    if (e < E) atomicAdd(&deg_src[src[e]], 1);
}

__global__ void norm_kernel(const int* __restrict__ deg_src, float* __restrict__ norm, int n) {
    int i = blockIdx.x * blockDim.x + threadIdx.x;
    if (i < n) norm[i] = rsqrtf(fmaxf((float)deg_src[i], 1.0f));
}

// Fixed-slot fill: cursor atomic IS the in-degree count. Slot overflow (practically
// never: in-degree ~Poisson(12.5), CAP>=24) goes to an overflow list.
__global__ void fill_slot_kernel(const int* __restrict__ src, const int* __restrict__ dst,
                                 int* __restrict__ cnt_dst, int* __restrict__ csr,
                                 int* __restrict__ ovf_cnt, int* __restrict__ ovf,
                                 int E, int cap) {
    int e = blockIdx.x * blockDim.x + threadIdx.x;
    if (e >= E) return;
    int s = src[e], t = dst[e];
    int pos = atomicAdd(&cnt_dst[t], 1);
    if (pos < cap) {
        csr[(size_t)t * cap + pos] = s;
    } else {
        int i = atomicAdd(ovf_cnt, 1);
        if (i < MAXOVF) { ovf[2 * i] = s; ovf[2 * i + 1] = t; }
    }
}

// One wave per node, lane = feature. Register accumulate, single coalesced write
// fused with EPS*x residual.
__global__ void gather_slot_kernel(const float* __restrict__ x, const int* __restrict__ csr,
                                   const int* __restrict__ cnt_dst, const float* __restrict__ norm,
                                   float* __restrict__ out, int n, int cap) {
    int node = blockIdx.x * (blockDim.x >> 6) + (threadIdx.x >> 6);
    int lane = threadIdx.x & 63;
    if (node >= n) return;
    int cnt = cnt_dst[node];
    if (cnt > cap) cnt = cap;
    const int* row = csr + (size_t)node * cap;
    float acc = 0.0f;
    int k = 0;
    for (; k + 1 < cnt; k += 2) {
        int s0 = row[k], s1 = row[k + 1];
        float a0 = norm[s0] * x[(size_t)s0 * D + lane];
        float a1 = norm[s1] * x[(size_t)s1 * D + lane];
        acc += a0 + a1;
    }
    if (k < cnt) { int s = row[k]; acc += norm[s] * x[(size_t)s * D + lane]; }
    out[(size_t)node * D + lane] = acc * norm[node] + EPS * x[(size_t)node * D + lane];
}

// Rare-path: add overflow edges with float atomics (runs after gather initialized out).
__global__ void cleanup_kernel(const float* __restrict__ x, const float* __restrict__ norm,
                               const int* __restrict__ ovf_cnt, const int* __restrict__ ovf,
                               float* __restrict__ out) {
    int cnt = *ovf_cnt;
    if (cnt > MAXOVF) cnt = MAXOVF;
    long long total = (long long)cnt * D;
    long long stride = (long long)gridDim.x * blockDim.x;
    for (long long i = blockIdx.x * (long long)blockDim.x + threadIdx.x; i < total; i += stride) {
        int e = (int)(i >> 6), d = (int)(i & 63);
        int s = ovf[2 * e], t = ovf[2 * e + 1];
        atomicAdd(&out[(size_t)t * D + d], norm[s] * norm[t] * x[(size_t)s * D + d]);
    }
}

// ---------------- Path B: compact CSR fallback (round-2 pipeline) ----------------

__global__ void hist2_kernel(const int* __restrict__ src, const int* __restrict__ dst,
                             int* __restrict__ deg_src, int* __restrict__ deg_dst, int E) {
    int e = blockIdx.x * blockDim.x + threadIdx.x;
    if (e < E) {
        atomicAdd(&deg_src[src[e]], 1);
        atomicAdd(&deg_dst[dst[e]], 1);
    }
}

__global__ void scan1_kernel(const int* __restrict__ deg_dst, int* __restrict__ row_excl,
                             int* __restrict__ block_sums, int n) {
    __shared__ int sh[SCAN_B];
    int i = blockIdx.x * SCAN_B + threadIdx.x;
    int v = (i < n) ? deg_dst[i] : 0;
    sh[threadIdx.x] = v;
    __syncthreads();
    for (int off = 1; off < SCAN_B; off <<= 1) {
        int t = (threadIdx.x >= off) ? sh[threadIdx.x - off] : 0;
        __syncthreads();
        sh[threadIdx.x] += t;
        __syncthreads();
    }
    if (i < n) row_excl[i] = sh[threadIdx.x] - v;
    if (threadIdx.x == SCAN_B - 1) block_sums[blockIdx.x] = sh[SCAN_B - 1];
}

__global__ void scan2_kernel(int* __restrict__ block_sums, int S) {
    __shared__ int sh[SCAN_B];
    int v = (threadIdx.x < S) ? block_sums[threadIdx.x] : 0;
    sh[threadIdx.x] = v;
    __syncthreads();
    for (int off = 1; off < SCAN_B; off <<= 1) {
        int t = (threadIdx.x >= off) ? sh[threadIdx.x - off] : 0;
        __syncthreads();
        sh[threadIdx.x] += t;
        __syncthreads();
    }
    if (threadIdx.x < S) block_sums[threadIdx.x] = sh[threadIdx.x] - v;
}

__global__ void scan3_kernel(int* __restrict__ row_excl, const int* __restrict__ block_sums,
                             int* __restrict__ cursor, int n) {
    int i = blockIdx.x * SCAN_B + threadIdx.x;
    if (i < n) {
        int r = row_excl[i] + block_sums[blockIdx.x];
        row_excl[i] = r;
        cursor[i] = r;
    }
}

__global__ void fill_compact_kernel(const int* __restrict__ src, const int* __restrict__ dst,
                                    int* __restrict__ cursor, int* __restrict__ csr_src, int E) {
    int e = blockIdx.x * blockDim.x + threadIdx.x;
    if (e < E) {
        int pos = atomicAdd(&cursor[dst[e]], 1);
        csr_src[pos] = src[e];
    }
}

__global__ void gather_compact_kernel(const float* __restrict__ x, const int* __restrict__ csr_src,
                                      const int* __restrict__ row_ptr, const int* __restrict__ row_end,
                                      const float* __restrict__ norm, float* __restrict__ out, int n) {
    int node = blockIdx.x * (blockDim.x >> 6) + (threadIdx.x >> 6);
    int lane = threadIdx.x & 63;
    if (node >= n) return;
    int k = row_ptr[node];
    int end = row_end[node];
    float acc = 0.0f;
    for (; k + 1 < end; k += 2) {
        int s0 = csr_src[k], s1 = csr_src[k + 1];
        float a0 = norm[s0] * x[(size_t)s0 * D + lane];
        float a1 = norm[s1] * x[(size_t)s1 * D + lane];
        acc += a0 + a1;
    }
    if (k < end) { int s = csr_src[k]; acc += norm[s] * x[(size_t)s * D + lane]; }
    out[(size_t)node * D + lane] = acc * norm[node] + EPS * x[(size_t)node * D + lane];
}

// ---------------- launcher ----------------

extern "C" void kernel_launch(void* const* d_in, const int* in_sizes, int n_in,
                              void* d_out, int out_size, void* d_ws, size_t ws_size,
                              hipStream_t stream) {
    const float* x   = (const float*)d_in[0];
    const int*   src = (const int*)d_in[1];
    const int*   dst = (const int*)d_in[2];
    float* out = (float*)d_out;

    const int ND = in_sizes[0];
    const int E  = in_sizes[1];
    const int n  = ND / D;
    constexpr int B = 256;

    // Pick largest fitting slot capacity (in-degree ~Poisson(12.5); CAP>=24 => ~0 overflow)
    int cap = 0;
    for (int c : {64, 48, 32, 24}) {
        size_t need = (size_t)4 * ((size_t)3 * n + 64 + 2 * (size_t)MAXOVF + (size_t)n * c);
        if (need <= ws_size) { cap = c; break; }
    }

    if (cap > 0) {
        // ---- Path A: fixed-slot CSR ----
        int*   deg_src = (int*)d_ws;             // [0, n)
        int*   cnt_dst = deg_src + n;            // [n, 2n)
        int*   ovf_cnt = cnt_dst + n;            // [2n, 2n+64) (64-int pad, [0] used)
        float* norm    = (float*)(ovf_cnt + 64); // n floats
        int*   ovf     = (int*)(norm + n);       // 2*MAXOVF ints
        int*   csr     = ovf + 2 * MAXOVF;       // n*cap ints

        // zero deg_src + cnt_dst + ovf_cnt in one memset (contiguous)
        hipMemsetAsync(deg_src, 0, (size_t)(2 * n + 64) * sizeof(int), stream);

        hist_src_kernel<<<(E + B - 1) / B, B, 0, stream>>>(src, deg_src, E);
        norm_kernel<<<(n + B - 1) / B, B, 0, stream>>>(deg_src, norm, n);
        fill_slot_kernel<<<(E + B - 1) / B, B, 0, stream>>>(src, dst, cnt_dst, csr, ovf_cnt, ovf, E, cap);
        gather_slot_kernel<<<(n + 3) / 4, B, 0, stream>>>(x, csr, cnt_dst, norm, out, n, cap);
        cleanup_kernel<<<64, B, 0, stream>>>(x, norm, ovf_cnt, ovf, out);
    } else {
        // ---- Path B: compact CSR (round-2 pipeline) ----
        const int S = (n + SCAN_B - 1) / SCAN_B;
        int*   deg_src    = (int*)d_ws;
        int*   deg_dst    = deg_src + n;
        float* norm       = (float*)(deg_dst + n);
        int*   row_ptr    = (int*)(norm + n);
        int*   cursor     = row_ptr + n;
        int*   block_sums = cursor + n;
        int*   csr_src    = block_sums + ((S + 63) & ~63);

        hipMemsetAsync(deg_src, 0, (size_t)2 * n * sizeof(int), stream);
        hist2_kernel<<<(E + B - 1) / B, B, 0, stream>>>(src, dst, deg_src, deg_dst, E);
        norm_kernel<<<(n + B - 1) / B, B, 0, stream>>>(deg_src, norm, n);
        scan1_kernel<<<S, SCAN_B, 0, stream>>>(deg_dst, row_ptr, block_sums, n);
        scan2_kernel<<<1, SCAN_B, 0, stream>>>(block_sums, S);
        scan3_kernel<<<S, SCAN_B, 0, stream>>>(row_ptr, block_sums, cursor, n);
        fill_compact_kernel<<<(E + B - 1) / B, B, 0, stream>>>(src, dst, cursor, csr_src, E);
        gather_compact_kernel<<<(n + 3) / 4, B, 0, stream>>>(x, csr_src, row_ptr, cursor, norm, out, n);
    }
}

// Round 4
// 269.471 us; speedup vs baseline: 1.5226x; 1.1529x over previous
//
#include <hip/hip_runtime.h>

// GCN aggregation: out = segsum_dst( x[src] * norm[src]*norm[dst] ) + EPS*x
// Round 4: (a) fuse the src-degree histogram into the CSR fill (one edge pass,
// not two); (b) gather from a bf16 copy of x (halves the random-row traffic,
// which is the gather's floor). bf16 error is scaled by norm[s]*norm[t]~0.08
// before summation -> worst-case output error ~5e-3, far under threshold.
constexpr int D = 64;
constexpr float EPS = 0.5f;
constexpr int SCAN_B = 1024;
constexpr int MAXOVF = 65536;   // overflow edge capacity (expected usage: ~0)

__device__ __forceinline__ unsigned short f2bf(float f) {
    unsigned int u = __float_as_uint(f);
    unsigned int r = (u + 0x7FFFu + ((u >> 16) & 1u)) >> 16;   // RNE
    return (unsigned short)r;
}
__device__ __forceinline__ float bf2f(unsigned short h) {
    return __uint_as_float(((unsigned int)h) << 16);
}

// ---------------- Path A: fused fixed-slot CSR + bf16 gather ----------------

// x (f32) -> xh (bf16), vectorized: float4 in, ushort4 out
__global__ void cvt_kernel(const float4* __restrict__ x, ushort4* __restrict__ xh, int n4) {
    int i = blockIdx.x * blockDim.x + threadIdx.x;
    if (i < n4) {
        float4 v = x[i];
        ushort4 h;
        h.x = f2bf(v.x); h.y = f2bf(v.y); h.z = f2bf(v.z); h.w = f2bf(v.w);
        xh[i] = h;
    }
}

// One pass over edges: src-degree histogram + fixed-slot CSR fill.
__global__ void fused_fill_kernel(const int* __restrict__ src, const int* __restrict__ dst,
                                  int* __restrict__ deg_src, int* __restrict__ cnt_dst,
                                  int* __restrict__ csr, int* __restrict__ ovf_cnt,
                                  int* __restrict__ ovf, int E, int cap) {
    int e = blockIdx.x * blockDim.x + threadIdx.x;
    if (e >= E) return;
    int s = src[e], t = dst[e];
    atomicAdd(&deg_src[s], 1);                    // fire-and-forget
    int pos = atomicAdd(&cnt_dst[t], 1);
    if (pos < cap) {
        csr[(size_t)t * cap + pos] = s;
    } else {
        int i = atomicAdd(ovf_cnt, 1);
        if (i < MAXOVF) { ovf[2 * i] = s; ovf[2 * i + 1] = t; }
    }
}

__global__ void norm_kernel(const int* __restrict__ deg_src, float* __restrict__ norm, int n) {
    int i = blockIdx.x * blockDim.x + threadIdx.x;
    if (i < n) norm[i] = rsqrtf(fmaxf((float)deg_src[i], 1.0f));
}

// One wave per node, lane = feature. bf16 x-rows (128B/row), f32 accumulate,
// single coalesced f32 write fused with the EPS*x residual (residual uses f32 x).
__global__ void gather_bf16_kernel(const unsigned short* __restrict__ xh,
                                   const float* __restrict__ x,
                                   const int* __restrict__ csr, const int* __restrict__ cnt_dst,
                                   const float* __restrict__ norm, float* __restrict__ out,
                                   int n, int cap) {
    int node = blockIdx.x * (blockDim.x >> 6) + (threadIdx.x >> 6);
    int lane = threadIdx.x & 63;
    if (node >= n) return;
    int cnt = cnt_dst[node];
    if (cnt > cap) cnt = cap;
    const int* row = csr + (size_t)node * cap;
    float acc = 0.0f;
    int k = 0;
    for (; k + 3 < cnt; k += 4) {
        int s0 = row[k], s1 = row[k + 1], s2 = row[k + 2], s3 = row[k + 3];
        float f0 = bf2f(xh[(size_t)s0 * D + lane]);
        float f1 = bf2f(xh[(size_t)s1 * D + lane]);
        float f2 = bf2f(xh[(size_t)s2 * D + lane]);
        float f3 = bf2f(xh[(size_t)s3 * D + lane]);
        acc += norm[s0] * f0 + norm[s1] * f1 + norm[s2] * f2 + norm[s3] * f3;
    }
    for (; k < cnt; ++k) {
        int s = row[k];
        acc += norm[s] * bf2f(xh[(size_t)s * D + lane]);
    }
    out[(size_t)node * D + lane] = acc * norm[node] + EPS * x[(size_t)node * D + lane];
}

// Rare-path: add overflow edges with float atomics (after gather wrote out).
__global__ void cleanup_kernel(const float* __restrict__ x, const float* __restrict__ norm,
                               const int* __restrict__ ovf_cnt, const int* __restrict__ ovf,
                               float* __restrict__ out) {
    int cnt = *ovf_cnt;
    if (cnt > MAXOVF) cnt = MAXOVF;
    long long total = (long long)cnt * D;
    long long stride = (long long)gridDim.x * blockDim.x;
    for (long long i = blockIdx.x * (long long)blockDim.x + threadIdx.x; i < total; i += stride) {
        int e = (int)(i >> 6), d = (int)(i & 63);
        int s = ovf[2 * e], t = ovf[2 * e + 1];
        atomicAdd(&out[(size_t)t * D + d], norm[s] * norm[t] * x[(size_t)s * D + d]);
    }
}

// ---------------- Path B: compact CSR fallback (round-2 pipeline, f32) ----------------

__global__ void hist2_kernel(const int* __restrict__ src, const int* __restrict__ dst,
                             int* __restrict__ deg_src, int* __restrict__ deg_dst, int E) {
    int e = blockIdx.x * blockDim.x + threadIdx.x;
    if (e < E) {
        atomicAdd(&deg_src[src[e]], 1);
        atomicAdd(&deg_dst[dst[e]], 1);
    }
}

__global__ void scan1_kernel(const int* __restrict__ deg_dst, int* __restrict__ row_excl,
                             int* __restrict__ block_sums, int n) {
    __shared__ int sh[SCAN_B];
    int i = blockIdx.x * SCAN_B + threadIdx.x;
    int v = (i < n) ? deg_dst[i] : 0;
    sh[threadIdx.x] = v;
    __syncthreads();
    for (int off = 1; off < SCAN_B; off <<= 1) {
        int t = (threadIdx.x >= off) ? sh[threadIdx.x - off] : 0;
        __syncthreads();
        sh[threadIdx.x] += t;
        __syncthreads();
    }
    if (i < n) row_excl[i] = sh[threadIdx.x] - v;
    if (threadIdx.x == SCAN_B - 1) block_sums[blockIdx.x] = sh[SCAN_B - 1];
}

__global__ void scan2_kernel(int* __restrict__ block_sums, int S) {
    __shared__ int sh[SCAN_B];
    int v = (threadIdx.x < S) ? block_sums[threadIdx.x] : 0;
    sh[threadIdx.x] = v;
    __syncthreads();
    for (int off = 1; off < SCAN_B; off <<= 1) {
        int t = (threadIdx.x >= off) ? sh[threadIdx.x - off] : 0;
        __syncthreads();
        sh[threadIdx.x] += t;
        __syncthreads();
    }
    if (threadIdx.x < S) block_sums[threadIdx.x] = sh[threadIdx.x] - v;
}

__global__ void scan3_kernel(int* __restrict__ row_excl, const int* __restrict__ block_sums,
                             int* __restrict__ cursor, int n) {
    int i = blockIdx.x * SCAN_B + threadIdx.x;
    if (i < n) {
        int r = row_excl[i] + block_sums[blockIdx.x];
        row_excl[i] = r;
        cursor[i] = r;
    }
}

__global__ void fill_compact_kernel(const int* __restrict__ src, const int* __restrict__ dst,
                                    int* __restrict__ cursor, int* __restrict__ csr_src, int E) {
    int e = blockIdx.x * blockDim.x + threadIdx.x;
    if (e < E) {
        int pos = atomicAdd(&cursor[dst[e]], 1);
        csr_src[pos] = src[e];
    }
}

__global__ void gather_compact_kernel(const float* __restrict__ x, const int* __restrict__ csr_src,
                                      const int* __restrict__ row_ptr, const int* __restrict__ row_end,
                                      const float* __restrict__ norm, float* __restrict__ out, int n) {
    int node = blockIdx.x * (blockDim.x >> 6) + (threadIdx.x >> 6);
    int lane = threadIdx.x & 63;
    if (node >= n) return;
    int k = row_ptr[node];
    int end = row_end[node];
    float acc = 0.0f;
    for (; k + 1 < end; k += 2) {
        int s0 = csr_src[k], s1 = csr_src[k + 1];
        acc += norm[s0] * x[(size_t)s0 * D + lane] + norm[s1] * x[(size_t)s1 * D + lane];
    }
    if (k < end) { int s = csr_src[k]; acc += norm[s] * x[(size_t)s * D + lane]; }
    out[(size_t)node * D + lane] = acc * norm[node] + EPS * x[(size_t)node * D + lane];
}

// ---------------- launcher ----------------

extern "C" void kernel_launch(void* const* d_in, const int* in_sizes, int n_in,
                              void* d_out, int out_size, void* d_ws, size_t ws_size,
                              hipStream_t stream) {
    const float* x   = (const float*)d_in[0];
    const int*   src = (const int*)d_in[1];
    const int*   dst = (const int*)d_in[2];
    float* out = (float*)d_out;

    const int ND = in_sizes[0];
    const int E  = in_sizes[1];
    const int n  = ND / D;
    constexpr int B = 256;

    // Fixed-slot capacity (in-degree ~Poisson(E/N); cap>=24 => overflow ~1e2 edges,
    // handled by cleanup). Prefer larger cap; include bf16 copy of x in the budget.
    int cap = 0;
    for (int c : {64, 48, 32, 24}) {
        size_t need = 4 * ((size_t)3 * n + 64 + 2 * (size_t)MAXOVF + (size_t)n * c)
                    + 2 * (size_t)ND;
        if (need <= ws_size) { cap = c; break; }
    }

    if (cap > 0) {
        // ---- Path A ----
        int*   deg_src = (int*)d_ws;                       // n
        int*   cnt_dst = deg_src + n;                      // n
        int*   ovf_cnt = cnt_dst + n;                      // 64 (pad; [0] used)
        float* norm    = (float*)(ovf_cnt + 64);           // n
        int*   ovf     = (int*)(norm + n);                 // 2*MAXOVF
        unsigned short* xh = (unsigned short*)(ovf + 2 * MAXOVF);  // ND bf16
        int*   csr     = (int*)(xh + ND);                  // n*cap (ND even -> 4B aligned)

        hipMemsetAsync(deg_src, 0, (size_t)(2 * n + 64) * sizeof(int), stream);

        cvt_kernel<<<(ND / 4 + B - 1) / B, B, 0, stream>>>((const float4*)x, (ushort4*)xh, ND / 4);
        fused_fill_kernel<<<(E + B - 1) / B, B, 0, stream>>>(src, dst, deg_src, cnt_dst, csr,
                                                             ovf_cnt, ovf, E, cap);
        norm_kernel<<<(n + B - 1) / B, B, 0, stream>>>(deg_src, norm, n);
        gather_bf16_kernel<<<(n + 3) / 4, B, 0, stream>>>(xh, x, csr, cnt_dst, norm, out, n, cap);
        cleanup_kernel<<<64, B, 0, stream>>>(x, norm, ovf_cnt, ovf, out);
    } else {
        // ---- Path B: compact CSR (f32) ----
        const int S = (n + SCAN_B - 1) / SCAN_B;
        int*   deg_src    = (int*)d_ws;
        int*   deg_dst    = deg_src + n;
        float* norm       = (float*)(deg_dst + n);
        int*   row_ptr    = (int*)(norm + n);
        int*   cursor     = row_ptr + n;
        int*   block_sums = cursor + n;
        int*   csr_src    = block_sums + ((S + 63) & ~63);

        hipMemsetAsync(deg_src, 0, (size_t)2 * n * sizeof(int), stream);
        hist2_kernel<<<(E + B - 1) / B, B, 0, stream>>>(src, dst, deg_src, deg_dst, E);
        norm_kernel<<<(n + B - 1) / B, B, 0, stream>>>(deg_src, norm, n);
        scan1_kernel<<<S, SCAN_B, 0, stream>>>(deg_dst, row_ptr, block_sums, n);
        scan2_kernel<<<1, SCAN_B, 0, stream>>>(block_sums, S);
        scan3_kernel<<<S, SCAN_B, 0, stream>>>(row_ptr, block_sums, cursor, n);
        fill_compact_kernel<<<(E + B - 1) / B, B, 0, stream>>>(src, dst, cursor, csr_src, E);
        gather_compact_kernel<<<(n + 3) / 4, B, 0, stream>>>(x, csr_src, row_ptr, cursor, norm, out, n);
    }
}